// Round 8
// baseline (266.005 us; speedup 1.0000x reference)
//
#include <hip/hip_runtime.h>
#include <hip/hip_bf16.h>
#include <stdint.h>

#define NBATCH 4
#define NV 2048
#define NC 8192
#define DD 64

typedef __attribute__((ext_vector_type(8))) short s16x8;
typedef __attribute__((ext_vector_type(4))) float fx4;
typedef __attribute__((ext_vector_type(8))) unsigned short u16x8;
typedef __attribute__((ext_vector_type(4))) int i32x4;
typedef __attribute__((ext_vector_type(2))) unsigned int u32x2;

static __device__ __forceinline__ unsigned short bf16_rne(float x) {
    union { float f; unsigned int u; } v; v.f = x;
    unsigned int u = v.u;
    u += 0x7FFFu + ((u >> 16) & 1u);
    return (unsigned short)(u >> 16);
}
static __device__ __forceinline__ float bf16_f32(unsigned short h) {
    union { unsigned int u; float f; } v; v.u = ((unsigned int)h) << 16;
    return v.f;
}

// ---------------------------------------------------------------------------
// K0: s=(pos+neg)/2, d=(pos-neg)/2 of variables @ c_block[pn]^T, quantized to
// int16 (scale 2^12), split hi/lo i8, stored in i8 MFMA B-frag layout:
// chunk kc (64 vars): 4096 B at (b*32+kc)*4096; within: dout*64 + lg*16 + half*8
// ---------------------------------------------------------------------------
__global__ __launch_bounds__(256) void k_prep_pv(
    const float* __restrict__ vars, const float* __restrict__ cblk,
    char* __restrict__ qsh, char* __restrict__ qsl,
    char* __restrict__ qdh, char* __restrict__ qdl)
{
    __shared__ float sv[32][64];
    __shared__ float scb[2][64][65];
    int blk = blockIdx.x;
    int b = blk >> 6, ch = blk & 63;
    int t = threadIdx.x;
    const float* vsrc = vars + ((size_t)b * NV + (size_t)ch * 32) * DD;
    for (int i = t; i < 32 * 64; i += 256) sv[i >> 6][i & 63] = vsrc[i];
    for (int i = t; i < 2 * 64 * 64; i += 256) {
        int pn = i >> 12, dout = (i >> 6) & 63, k = i & 63;
        scb[pn][k][dout] = cblk[i];
    }
    __syncthreads();
    int ks = t >> 6, dout = t & 63;
    unsigned int wsh[2] = {0, 0}, wsl[2] = {0, 0}, wdh[2] = {0, 0}, wdl[2] = {0, 0};
    #pragma unroll
    for (int c8 = 0; c8 < 8; ++c8) {
        int vloc = ks * 8 + c8;
        float ap = 0.f, an = 0.f;
        for (int k = 0; k < 64; ++k) {
            float vv = sv[vloc][k];
            ap += vv * scb[0][k][dout];
            an += vv * scb[1][k][dout];
        }
        float s = (ap + an) * 0.5f, dv = (ap - an) * 0.5f;
        int qs_ = (int)rintf(s * 4096.f);
        int qd_ = (int)rintf(dv * 4096.f);
        qs_ = min(max(qs_, -32511), 32511);
        qd_ = min(max(qd_, -32511), 32511);
        int sh = (qs_ + 128) >> 8, sl = qs_ - (sh << 8);
        int dh = (qd_ + 128) >> 8, dl = qd_ - (dh << 8);
        int w = c8 >> 2, sft = (c8 & 3) * 8;
        wsh[w] |= (unsigned int)(sh & 0xFF) << sft;
        wsl[w] |= (unsigned int)(sl & 0xFF) << sft;
        wdh[w] |= (unsigned int)(dh & 0xFF) << sft;
        wdl[w] |= (unsigned int)(dl & 0xFF) << sft;
    }
    int kc = ch >> 1;
    int lg = ((ch & 1) << 1) | (ks >> 1);
    size_t off = (((size_t)(b * 32 + kc) * 64 + dout) * 4 + lg) * 16 + (ks & 1) * 8;
    *(u32x2*)(qsh + off) = (u32x2){wsh[0], wsh[1]};
    *(u32x2*)(qsl + off) = (u32x2){wsl[0], wsl[1]};
    *(u32x2*)(qdh + off) = (u32x2){wdh[0], wdh[1]};
    *(u32x2*)(qdl + off) = (u32x2){wdl[0], wdl[1]};
}

// ---------------------------------------------------------------------------
// K1: i8 phase A, NO LDS / NO BARRIERS. cpart[q][b][c][d] = (|A|@s + A@d)
// raw i32-scaled partial over K-half q. 64-row 4-wave blocks, each wave an
// independent 16-row strip; B-frags read direct (L2-resident, coalesced).
// Emits comp 2-bit codes. grid 1024 x 256; blk&7 = b*2+q -> same XCD.
// ---------------------------------------------------------------------------
__global__ __launch_bounds__(256, 4) void k_phaseA(
    const float* __restrict__ cmat,
    const char* __restrict__ qsh, const char* __restrict__ qsl,
    const char* __restrict__ qdh, const char* __restrict__ qdl,
    float* __restrict__ cpart, unsigned short* __restrict__ comp)
{
    int blk = blockIdx.x;
    int combo = blk & 7;
    int rg = blk >> 3;
    int b = combo >> 1;
    int q = combo & 1;
    int t = threadIdx.x;
    int wv = t >> 6, l = t & 63, lr = l & 15, lg = l >> 4;
    int row = rg * 64 + wv * 16 + lr;
    const float* A0 = cmat + (size_t)b * NC * NV + (size_t)row * NV + q * 1024 + lg * 16;
    unsigned short* compb = comp + (size_t)b * 256 * NC;
    const char* qb0 = qsh + ((size_t)(b * 32 + q * 16)) * 4096;
    const char* qb1 = qsl + ((size_t)(b * 32 + q * 16)) * 4096;
    const char* qb2 = qdh + ((size_t)(b * 32 + q * 16)) * 4096;
    const char* qb3 = qdl + ((size_t)(b * 32 + q * 16)) * 4096;

    i32x4 ahi[4], alo[4];
    #pragma unroll
    for (int n = 0; n < 4; ++n) { ahi[n] = (i32x4){0,0,0,0}; alo[n] = (i32x4){0,0,0,0}; }

    #pragma unroll 1
    for (int kc = 0; kc < 16; ++kc) {
        fx4 xc[4];
        #pragma unroll
        for (int j4 = 0; j4 < 4; ++j4)
            xc[j4] = *(const fx4*)(A0 + kc * 64 + j4 * 4);
        int tt[16];
        #pragma unroll
        for (int j = 0; j < 16; ++j) tt[j] = (int)xc[j >> 2][j & 3];
        i32x4 Asgn, Aabs;
        #pragma unroll
        for (int w = 0; w < 4; ++w)
            Asgn[w] = (unsigned int)(tt[4*w] & 0xFF) | ((unsigned int)(tt[4*w+1] & 0xFF) << 8)
                    | ((unsigned int)(tt[4*w+2] & 0xFF) << 16) | ((unsigned int)(tt[4*w+3] & 0xFF) << 24);
        #pragma unroll
        for (int w = 0; w < 4; ++w) Aabs[w] = Asgn[w] & 0x01010101;
        {
            unsigned int b0 = 0, b1 = 0;
            #pragma unroll
            for (int j = 0; j < 8; ++j) b0 |= ((unsigned int)tt[j] & 3u) << (2 * j);
            #pragma unroll
            for (int j = 0; j < 8; ++j) b1 |= ((unsigned int)tt[8 + j] & 3u) << (2 * j);
            int v8 = q * 128 + kc * 8 + lg * 2;
            compb[(size_t)v8 * NC + row] = (unsigned short)b0;
            compb[(size_t)(v8 + 1) * NC + row] = (unsigned short)b1;
        }
        size_t cb_ = (size_t)kc * 4096;
        #pragma unroll
        for (int n = 0; n < 4; ++n) {
            size_t boff = cb_ + (size_t)(((n * 16 + lr) * 4 + lg) * 16);
            i32x4 Bsh = *(const i32x4*)(qb0 + boff);
            i32x4 Bsl = *(const i32x4*)(qb1 + boff);
            i32x4 Bdh = *(const i32x4*)(qb2 + boff);
            i32x4 Bdl = *(const i32x4*)(qb3 + boff);
            ahi[n] = __builtin_amdgcn_mfma_i32_16x16x64_i8(Aabs, Bsh, ahi[n], 0, 0, 0);
            ahi[n] = __builtin_amdgcn_mfma_i32_16x16x64_i8(Asgn, Bdh, ahi[n], 0, 0, 0);
            alo[n] = __builtin_amdgcn_mfma_i32_16x16x64_i8(Aabs, Bsl, alo[n], 0, 0, 0);
            alo[n] = __builtin_amdgcn_mfma_i32_16x16x64_i8(Asgn, Bdl, alo[n], 0, 0, 0);
        }
    }
    float* dst = cpart + (((size_t)q * NBATCH + b) * NC + rg * 64 + wv * 16) * DD;
    #pragma unroll
    for (int n = 0; n < 4; ++n) {
        int col = n * 16 + lr;
        #pragma unroll
        for (int r = 0; r < 4; ++r) {
            float v = (float)(ahi[n][r] * 256 + alo[n][r]) * (1.0f / 4096.0f);
            dst[(size_t)(lg * 4 + r) * DD + col] = v;
        }
    }
}

// ---------------------------------------------------------------------------
// K2: c = relu(sum_{q<2} cpart + cb); emit (c@v0^T +/- c@v1^T)/2 hi/lo bf16
// ---------------------------------------------------------------------------
__global__ __launch_bounds__(256) void k_projC(
    const float* __restrict__ cpart, const float* __restrict__ cb,
    const float* __restrict__ vblk,
    unsigned short* __restrict__ csh, unsigned short* __restrict__ csl,
    unsigned short* __restrict__ cdh, unsigned short* __restrict__ cdl)
{
    __shared__ float src[32][64];
    __shared__ float svb[2][64][65];
    int blk = blockIdx.x;
    int b = blk >> 8, kc = blk & 255;
    int t = threadIdx.x;
    const size_t qs = (size_t)NBATCH * NC * DD;
    const float* cs = cpart + ((size_t)b * NC + (size_t)kc * 32) * DD;
    for (int i = t; i < 2048; i += 256) {
        int k = i & 63;
        float v = cs[i] + cs[i + qs] + cb[k];
        src[i >> 6][k] = fmaxf(v, 0.f);
    }
    for (int i = t; i < 8192; i += 256) {
        int pn = i >> 12, dout = (i >> 6) & 63, k = i & 63;
        svb[pn][k][dout] = vblk[i];
    }
    __syncthreads();
    int ks = t >> 6, dout = t & 63;
    float ap[8] = {0.f, 0.f, 0.f, 0.f, 0.f, 0.f, 0.f, 0.f};
    float an[8] = {0.f, 0.f, 0.f, 0.f, 0.f, 0.f, 0.f, 0.f};
    for (int k = 0; k < 64; ++k) {
        float w0 = svb[0][k][dout], w1 = svb[1][k][dout];
        #pragma unroll
        for (int c8 = 0; c8 < 8; ++c8) {
            float rc = src[ks * 8 + c8][k];
            ap[c8] += rc * w0;
            an[c8] += rc * w1;
        }
    }
    u16x8 vsh, vsl, vdh, vdl;
    #pragma unroll
    for (int c8 = 0; c8 < 8; ++c8) {
        float s = (ap[c8] + an[c8]) * 0.5f, dv = (ap[c8] - an[c8]) * 0.5f;
        unsigned short h = bf16_rne(s);
        vsh[c8] = h; vsl[c8] = bf16_rne(s - bf16_f32(h));
        h = bf16_rne(dv);
        vdh[c8] = h; vdl[c8] = bf16_rne(dv - bf16_f32(h));
    }
    size_t obase = (size_t)b * NC * DD + (((size_t)kc * 4 + ks) * 64 + dout) * 8;
    *(u16x8*)(csh + obase) = vsh;
    *(u16x8*)(csl + obase) = vsl;
    *(u16x8*)(cdh + obase) = vdh;
    *(u16x8*)(cdl + obase) = vdl;
}

// ---------------------------------------------------------------------------
// K3: bf16 phase B, NO LDS / NO BARRIERS. npart[q][b][v][d] over K-eighth q.
// 64-row 4-wave blocks, 16-row strips, B-frags direct from L2.
// grid 1024 x 256; blk&31 = b*8+q -> same XCD per (b,q).
// ---------------------------------------------------------------------------
__global__ __launch_bounds__(256, 4) void k_phaseB(
    const unsigned short* __restrict__ comp,
    const unsigned short* __restrict__ csh, const unsigned short* __restrict__ csl,
    const unsigned short* __restrict__ cdh, const unsigned short* __restrict__ cdl,
    float* __restrict__ npart)
{
    int blk = blockIdx.x;
    int combo = blk & 31;
    int rg = blk >> 5;
    int b = combo >> 3;
    int q = combo & 7;
    int t = threadIdx.x;
    int wv = t >> 6, l = t & 63, lr = l & 15, lg = l >> 4;
    int v0 = rg * 64 + wv * 16;
    const unsigned short* compb = comp + (size_t)b * 256 * NC;
    const unsigned short* cp = compb + (size_t)((v0 + lr) >> 3) * NC + q * 1024 + lg * 8;
    int sh_ = 2 * (lr & 7);
    const size_t cvb = (size_t)b * NC * DD;
    const unsigned short* pb0 = csh + cvb + (size_t)(q * 16) * 4096;
    const unsigned short* pb1 = csl + cvb + (size_t)(q * 16) * 4096;
    const unsigned short* pb2 = cdh + cvb + (size_t)(q * 16) * 4096;
    const unsigned short* pb3 = cdl + cvb + (size_t)(q * 16) * 4096;

    fx4 acc[4];
    #pragma unroll
    for (int n = 0; n < 4; ++n) acc[n] = (fx4){0.f, 0.f, 0.f, 0.f};

    #pragma unroll 1
    for (int kc = 0; kc < 16; ++kc) {
        u16x8 uc0 = *(const u16x8*)(cp + kc * 64);
        u16x8 uc1 = *(const u16x8*)(cp + kc * 64 + 32);
        size_t cb_ = (size_t)kc * 4096;
        #pragma unroll
        for (int st = 0; st < 2; ++st) {
            u16x8 u = st ? uc1 : uc0;
            s16x8 As, Aa;
            #pragma unroll
            for (int i = 0; i < 8; ++i) {
                unsigned int tb = ((unsigned int)u[i] >> sh_) & 3u;
                unsigned short m = (tb & 1u) ? (unsigned short)0x3F80 : (unsigned short)0;
                As[i] = (short)m;
                Aa[i] = (short)(m | ((tb & 2u) << 14));
            }
            #pragma unroll
            for (int n = 0; n < 4; ++n) {
                size_t off = cb_ + (size_t)(((st * 4 + lg) * 64 + n * 16 + lr) * 8);
                s16x8 Bs0 = *(const s16x8*)(pb0 + off);
                s16x8 Bs1 = *(const s16x8*)(pb1 + off);
                s16x8 Bd0 = *(const s16x8*)(pb2 + off);
                s16x8 Bd1 = *(const s16x8*)(pb3 + off);
                acc[n] = __builtin_amdgcn_mfma_f32_16x16x32_bf16(As, Bs0, acc[n], 0, 0, 0);
                acc[n] = __builtin_amdgcn_mfma_f32_16x16x32_bf16(As, Bs1, acc[n], 0, 0, 0);
                acc[n] = __builtin_amdgcn_mfma_f32_16x16x32_bf16(Aa, Bd0, acc[n], 0, 0, 0);
                acc[n] = __builtin_amdgcn_mfma_f32_16x16x32_bf16(Aa, Bd1, acc[n], 0, 0, 0);
            }
        }
    }
    float* dst = npart + (((size_t)q * NBATCH + b) * NV + v0) * DD;
    #pragma unroll
    for (int n = 0; n < 4; ++n)
        #pragma unroll
        for (int r = 0; r < 4; ++r)
            dst[(size_t)(lg * 4 + r) * DD + n * 16 + lr] = acc[n][r];
}

// ---------------------------------------------------------------------------
// K4: v_emb=relu(sum_{q<8} npart+vb); av=tanh([g|v_emb]@Wg^T+bg); GRU -> out
// grid 512 x 512, 2 row-iterations per block.
// ---------------------------------------------------------------------------
__global__ __launch_bounds__(512) void k_gru(
    const float* __restrict__ npart, const float* __restrict__ vars,
    const float* __restrict__ gv, const float* __restrict__ vb,
    const float* __restrict__ Wg, const float* __restrict__ bg,
    const float* __restrict__ Wz, const float* __restrict__ Uz, const float* __restrict__ bz,
    const float* __restrict__ Wr, const float* __restrict__ Ur, const float* __restrict__ brr,
    const float* __restrict__ Wh, const float* __restrict__ Uh, const float* __restrict__ bh,
    float* __restrict__ out)
{
    __shared__ float sWg[72][65];
    __shared__ float sWz[64][65], sUz[64][65];
    __shared__ float sWr[64][65], sUr[64][65];
    __shared__ float sWh[64][65], sUh[64][65];
    __shared__ float scat[8][72];
    __shared__ float sprev[8][64];
    __shared__ float sav[8][64];
    __shared__ float srp[8][64];
    int t = threadIdx.x;
    for (int i = t * 4; i < 4608; i += 2048) {
        fx4 g4 = *(const fx4*)(Wg + i);
        int dout = i / 72, j = i - dout * 72;
        #pragma unroll
        for (int jj = 0; jj < 4; ++jj) sWg[j + jj][dout] = g4[jj];
    }
    for (int i = t * 4; i < 4096; i += 2048) {
        int dout = i >> 6, k = i & 63;
        fx4 a;
        a = *(const fx4*)(Wz + i);
        #pragma unroll
        for (int jj = 0; jj < 4; ++jj) sWz[k + jj][dout] = a[jj];
        a = *(const fx4*)(Uz + i);
        #pragma unroll
        for (int jj = 0; jj < 4; ++jj) sUz[k + jj][dout] = a[jj];
        a = *(const fx4*)(Wr + i);
        #pragma unroll
        for (int jj = 0; jj < 4; ++jj) sWr[k + jj][dout] = a[jj];
        a = *(const fx4*)(Ur + i);
        #pragma unroll
        for (int jj = 0; jj < 4; ++jj) sUr[k + jj][dout] = a[jj];
        a = *(const fx4*)(Wh + i);
        #pragma unroll
        for (int jj = 0; jj < 4; ++jj) sWh[k + jj][dout] = a[jj];
        a = *(const fx4*)(Uh + i);
        #pragma unroll
        for (int jj = 0; jj < 4; ++jj) sUh[k + jj][dout] = a[jj];
    }
    int rr = t >> 6, dout = t & 63;
    const size_t qs = (size_t)NBATCH * NV * DD;
    #pragma unroll 1
    for (int it = 0; it < 2; ++it) {
        size_t row = (size_t)blockIdx.x * 16 + it * 8 + rr;
        float prev = vars[row * 64 + dout];
        float ve = vb[dout];
        #pragma unroll
        for (int s = 0; s < 8; ++s) ve += npart[(size_t)s * qs + row * 64 + dout];
        ve = fmaxf(ve, 0.f);
        scat[rr][8 + dout] = ve;
        if (dout < 8) scat[rr][dout] = gv[row * 8 + dout];
        sprev[rr][dout] = prev;
        __syncthreads();
        float a = bg[dout];
        for (int j = 0; j < 72; ++j) a += scat[rr][j] * sWg[j][dout];
        float av = 1.f - 2.f / (__expf(2.f * a) + 1.f);
        sav[rr][dout] = av;
        __syncthreads();
        float zi = bz[dout], ri = brr[dout], hwa = 0.f;
        for (int k = 0; k < 64; ++k) {
            float ak = sav[rr][k], pk = sprev[rr][k];
            zi += ak * sWz[k][dout] + pk * sUz[k][dout];
            ri += ak * sWr[k][dout] + pk * sUr[k][dout];
            hwa += ak * sWh[k][dout];
        }
        float z = 1.f / (1.f + __expf(-zi));
        float rgate = 1.f / (1.f + __expf(-ri));
        srp[rr][dout] = rgate * prev;
        __syncthreads();
        float hin = bh[dout] + hwa;
        for (int k = 0; k < 64; ++k) hin += srp[rr][k] * sUh[k][dout];
        float ht = 1.f - 2.f / (__expf(2.f * hin) + 1.f);
        out[row * 64 + dout] = (1.f - z) * prev + z * ht;
        __syncthreads();
    }
}

// ---------------------------------------------------------------------------
extern "C" void kernel_launch(void* const* d_in, const int* in_sizes, int n_in,
                              void* d_out, int out_size, void* d_ws, size_t ws_size,
                              hipStream_t stream) {
    (void)in_sizes; (void)n_in; (void)out_size; (void)ws_size;
    const float* vars = (const float*)d_in[0];
    const float* gv   = (const float*)d_in[1];
    const float* cmat = (const float*)d_in[2];
    const float* cblk = (const float*)d_in[4];
    const float* vblk = (const float*)d_in[5];
    const float* vb   = (const float*)d_in[6];
    const float* cb   = (const float*)d_in[7];
    const float* Wg   = (const float*)d_in[8];
    const float* bg   = (const float*)d_in[9];
    const float* Wz   = (const float*)d_in[10];
    const float* Uz   = (const float*)d_in[11];
    const float* bz   = (const float*)d_in[12];
    const float* Wr   = (const float*)d_in[13];
    const float* Ur   = (const float*)d_in[14];
    const float* br_  = (const float*)d_in[15];
    const float* Wh   = (const float*)d_in[16];
    const float* Uh   = (const float*)d_in[17];
    const float* bh   = (const float*)d_in[18];
    float* out = (float*)d_out;

    char* w = (char*)d_ws;
    const size_t MB = 1024 * 1024;
    char* qsh = w + 0 * MB;
    char* qsl = w + 1 * MB;
    char* qdh = w + 2 * MB;
    char* qdl = w + 3 * MB;
    unsigned short* csh = (unsigned short*)(w + 4 * MB);
    unsigned short* csl = (unsigned short*)(w + 8 * MB);
    unsigned short* cdh = (unsigned short*)(w + 12 * MB);
    unsigned short* cdl = (unsigned short*)(w + 16 * MB);
    float* cpart         = (float*)(w + 20 * MB);           // 16 MB [2][B][NC][DD]
    float* npart         = (float*)(w + 36 * MB);           // 16 MB [8][B][NV][DD]
    unsigned short* comp = (unsigned short*)(w + 52 * MB);  // 16 MB [B][256][NC]

    k_prep_pv<<<256, 256, 0, stream>>>(vars, cblk, qsh, qsl, qdh, qdl);
    k_phaseA<<<1024, 256, 0, stream>>>(cmat, qsh, qsl, qdh, qdl, cpart, comp);
    k_projC<<<1024, 256, 0, stream>>>(cpart, cb, vblk, csh, csl, cdh, cdl);
    k_phaseB<<<1024, 256, 0, stream>>>(comp, csh, csl, cdh, cdl, npart);
    k_gru<<<512, 512, 0, stream>>>(npart, vars, gv, vb, Wg, bg,
                                   Wz, Uz, bz, Wr, Ur, br_, Wh, Uh, bh, out);
}

// Round 9
// 165.397 us; speedup vs baseline: 1.6083x; 1.6083x over previous
//
#include <hip/hip_runtime.h>
#include <hip/hip_bf16.h>
#include <stdint.h>

#define NBATCH 4
#define NV 2048
#define NC 8192
#define DD 64

typedef __attribute__((ext_vector_type(8))) short s16x8;
typedef __attribute__((ext_vector_type(4))) float fx4;
typedef __attribute__((ext_vector_type(8))) unsigned short u16x8;
typedef __attribute__((ext_vector_type(4))) int i32x4;
typedef __attribute__((ext_vector_type(2))) unsigned int u32x2;

static __device__ __forceinline__ void gload_lds16(const void* g, void* l) {
    __builtin_amdgcn_global_load_lds(
        (const __attribute__((address_space(1))) unsigned int*)g,
        (__attribute__((address_space(3))) unsigned int*)l, 16, 0, 0);
}

// ---------------------------------------------------------------------------
// K0: s=(pos+neg)/2, d=(pos-neg)/2 of variables @ c_block[pn]^T, quantized to
// int16 (scale 2^12), split hi/lo i8, i8 MFMA B-frag layout:
// chunk kc (64 vars): 4096 B at (b*32+kc)*4096; within: (dout*4+lg)*16 + j
// ---------------------------------------------------------------------------
__global__ __launch_bounds__(256) void k_prep_pv(
    const float* __restrict__ vars, const float* __restrict__ cblk,
    char* __restrict__ qsh, char* __restrict__ qsl,
    char* __restrict__ qdh, char* __restrict__ qdl)
{
    __shared__ float sv[32][64];
    __shared__ float scb[2][64][65];
    int blk = blockIdx.x;
    int b = blk >> 6, ch = blk & 63;
    int t = threadIdx.x;
    const float* vsrc = vars + ((size_t)b * NV + (size_t)ch * 32) * DD;
    for (int i = t; i < 32 * 64; i += 256) sv[i >> 6][i & 63] = vsrc[i];
    for (int i = t; i < 2 * 64 * 64; i += 256) {
        int pn = i >> 12, dout = (i >> 6) & 63, k = i & 63;
        scb[pn][k][dout] = cblk[i];
    }
    __syncthreads();
    int ks = t >> 6, dout = t & 63;
    unsigned int wsh[2] = {0, 0}, wsl[2] = {0, 0}, wdh[2] = {0, 0}, wdl[2] = {0, 0};
    #pragma unroll
    for (int c8 = 0; c8 < 8; ++c8) {
        int vloc = ks * 8 + c8;
        float ap = 0.f, an = 0.f;
        for (int k = 0; k < 64; ++k) {
            float vv = sv[vloc][k];
            ap += vv * scb[0][k][dout];
            an += vv * scb[1][k][dout];
        }
        float s = (ap + an) * 0.5f, dv = (ap - an) * 0.5f;
        int qs_ = (int)rintf(s * 4096.f);
        int qd_ = (int)rintf(dv * 4096.f);
        qs_ = min(max(qs_, -32511), 32511);
        qd_ = min(max(qd_, -32511), 32511);
        int sh = (qs_ + 128) >> 8, sl = qs_ - (sh << 8);
        int dh = (qd_ + 128) >> 8, dl = qd_ - (dh << 8);
        int w = c8 >> 2, sft = (c8 & 3) * 8;
        wsh[w] |= (unsigned int)(sh & 0xFF) << sft;
        wsl[w] |= (unsigned int)(sl & 0xFF) << sft;
        wdh[w] |= (unsigned int)(dh & 0xFF) << sft;
        wdl[w] |= (unsigned int)(dl & 0xFF) << sft;
    }
    int kc = ch >> 1;
    int lg = ((ch & 1) << 1) | (ks >> 1);
    size_t off = (((size_t)(b * 32 + kc) * 64 + dout) * 4 + lg) * 16 + (ks & 1) * 8;
    *(u32x2*)(qsh + off) = (u32x2){wsh[0], wsh[1]};
    *(u32x2*)(qsl + off) = (u32x2){wsl[0], wsl[1]};
    *(u32x2*)(qdh + off) = (u32x2){wdh[0], wdh[1]};
    *(u32x2*)(qdl + off) = (u32x2){wdl[0], wdl[1]};
}

// ---------------------------------------------------------------------------
// K1: i8 phase A (r6 form, unchanged). cpart[q][b][c][d] raw-scaled partial,
// 128-row 4-wave blocks, K-quarter q, gload_lds double-buffer, comp codes.
// grid 1024 x 256.
// ---------------------------------------------------------------------------
__global__ __launch_bounds__(256, 2) void k_phaseA(
    const float* __restrict__ cmat,
    const char* __restrict__ qsh, const char* __restrict__ qsl,
    const char* __restrict__ qdh, const char* __restrict__ qdl,
    float* __restrict__ cpart, unsigned short* __restrict__ comp)
{
    __shared__ char lds[2][16384];
    int blk = blockIdx.x;
    int combo = blk & 15;
    int rg = blk >> 4;
    int b = combo >> 2;
    int q = combo & 3;
    int t = threadIdx.x;
    int wv = t >> 6, l = t & 63, lr = l & 15, lg = l >> 4;
    int c0 = rg * 128 + wv * 32;
    const float* A0 = cmat + (size_t)b * NC * NV + (size_t)lr * NV + q * 512 + lg * 16;
    unsigned short* compb = comp + (size_t)b * 256 * NC;

    i32x4 ahi[2][4], alo[2][4];
    #pragma unroll
    for (int i = 0; i < 2; ++i)
        #pragma unroll
        for (int j = 0; j < 4; ++j) { ahi[i][j] = (i32x4){0,0,0,0}; alo[i][j] = (i32x4){0,0,0,0}; }

    {
        size_t gb = ((size_t)(b * 32 + q * 8)) * 4096 + (size_t)t * 16;
        char* lp = &lds[0][t * 16];
        gload_lds16(qsh + gb, lp);
        gload_lds16(qsl + gb, lp + 4096);
        gload_lds16(qdh + gb, lp + 8192);
        gload_lds16(qdl + gb, lp + 12288);
    }
    fx4 xc[2][4], xn[2][4];
    #pragma unroll
    for (int rt = 0; rt < 2; ++rt)
        #pragma unroll
        for (int j4 = 0; j4 < 4; ++j4)
            xc[rt][j4] = *(const fx4*)(A0 + (size_t)(c0 + rt * 16) * NV + j4 * 4);
    __syncthreads();

    int cur = 0;
    #pragma unroll 1
    for (int cc = 0; cc < 8; ++cc) {
        if (cc < 7) {
            size_t gb = ((size_t)(b * 32 + q * 8 + cc + 1)) * 4096 + (size_t)t * 16;
            char* lp = &lds[cur ^ 1][t * 16];
            gload_lds16(qsh + gb, lp);
            gload_lds16(qsl + gb, lp + 4096);
            gload_lds16(qdh + gb, lp + 8192);
            gload_lds16(qdl + gb, lp + 12288);
            #pragma unroll
            for (int rt = 0; rt < 2; ++rt)
                #pragma unroll
                for (int j4 = 0; j4 < 4; ++j4)
                    xn[rt][j4] = *(const fx4*)(A0 + (size_t)(c0 + rt * 16) * NV + (cc + 1) * 64 + j4 * 4);
        }
        i32x4 Asgn[2], Aabs[2];
        #pragma unroll
        for (int rt = 0; rt < 2; ++rt) {
            int tt[16];
            #pragma unroll
            for (int j = 0; j < 16; ++j) tt[j] = (int)xc[rt][j >> 2][j & 3];
            i32x4 sg;
            #pragma unroll
            for (int w = 0; w < 4; ++w)
                sg[w] = (unsigned int)(tt[4*w] & 0xFF) | ((unsigned int)(tt[4*w+1] & 0xFF) << 8)
                      | ((unsigned int)(tt[4*w+2] & 0xFF) << 16) | ((unsigned int)(tt[4*w+3] & 0xFF) << 24);
            Asgn[rt] = sg;
            i32x4 ab;
            #pragma unroll
            for (int w = 0; w < 4; ++w) ab[w] = sg[w] & 0x01010101;
            Aabs[rt] = ab;
            unsigned int b0 = 0, b1 = 0;
            #pragma unroll
            for (int j = 0; j < 8; ++j) b0 |= ((unsigned int)tt[j] & 3u) << (2 * j);
            #pragma unroll
            for (int j = 0; j < 8; ++j) b1 |= ((unsigned int)tt[8 + j] & 3u) << (2 * j);
            int v8 = q * 64 + cc * 8 + lg * 2;
            int crow = c0 + rt * 16 + lr;
            compb[(size_t)v8 * NC + crow] = (unsigned short)b0;
            compb[(size_t)(v8 + 1) * NC + crow] = (unsigned short)b1;
        }
        const char* bufp = lds[cur];
        #pragma unroll
        for (int n = 0; n < 4; ++n) {
            int boff = ((n * 16 + lr) * 4 + lg) * 16;
            i32x4 Bsh = *(const i32x4*)(bufp + boff);
            i32x4 Bsl = *(const i32x4*)(bufp + 4096 + boff);
            i32x4 Bdh = *(const i32x4*)(bufp + 8192 + boff);
            i32x4 Bdl = *(const i32x4*)(bufp + 12288 + boff);
            #pragma unroll
            for (int rt = 0; rt < 2; ++rt) {
                ahi[rt][n] = __builtin_amdgcn_mfma_i32_16x16x64_i8(Aabs[rt], Bsh, ahi[rt][n], 0, 0, 0);
                ahi[rt][n] = __builtin_amdgcn_mfma_i32_16x16x64_i8(Asgn[rt], Bdh, ahi[rt][n], 0, 0, 0);
                alo[rt][n] = __builtin_amdgcn_mfma_i32_16x16x64_i8(Aabs[rt], Bsl, alo[rt][n], 0, 0, 0);
                alo[rt][n] = __builtin_amdgcn_mfma_i32_16x16x64_i8(Asgn[rt], Bdl, alo[rt][n], 0, 0, 0);
            }
        }
        if (cc < 7) {
            #pragma unroll
            for (int rt = 0; rt < 2; ++rt)
                #pragma unroll
                for (int j4 = 0; j4 < 4; ++j4) xc[rt][j4] = xn[rt][j4];
        }
        __syncthreads();
        cur ^= 1;
    }
    float* dst = cpart + (((size_t)q * NBATCH + b) * NC + c0) * DD;
    #pragma unroll
    for (int rt = 0; rt < 2; ++rt)
        #pragma unroll
        for (int n = 0; n < 4; ++n)
            #pragma unroll
            for (int r = 0; r < 4; ++r) {
                float v = (float)(ahi[rt][n][r] * 256 + alo[rt][n][r]) * (1.0f / 4096.0f);
                dst[(size_t)(rt * 16 + lg * 4 + r) * DD + n * 16 + lr] = v;
            }
}

// ---------------------------------------------------------------------------
// K2: c = relu(sum_q cpart + cb); emit (c@v0^T +/- c@v1^T)/2 quantized int16
// (scale 2^9), split hi/lo i8, i8 B-frag layout (chunk = 64 clauses, 4096 B).
// ---------------------------------------------------------------------------
__global__ __launch_bounds__(256) void k_projC(
    const float* __restrict__ cpart, const float* __restrict__ cb,
    const float* __restrict__ vblk,
    char* __restrict__ csh, char* __restrict__ csl,
    char* __restrict__ cdh, char* __restrict__ cdl)
{
    __shared__ float src[32][64];
    __shared__ float svb[2][64][65];
    int blk = blockIdx.x;
    int b = blk >> 8, kc32 = blk & 255;
    int t = threadIdx.x;
    const size_t qs = (size_t)NBATCH * NC * DD;
    const float* cs = cpart + ((size_t)b * NC + (size_t)kc32 * 32) * DD;
    for (int i = t; i < 2048; i += 256) {
        int k = i & 63;
        float v = cb[k];
        #pragma unroll
        for (int p = 0; p < 4; ++p) v += cs[i + p * qs];
        src[i >> 6][k] = fmaxf(v, 0.f);
    }
    for (int i = t; i < 8192; i += 256) {
        int pn = i >> 12, dout = (i >> 6) & 63, k = i & 63;
        svb[pn][k][dout] = vblk[i];
    }
    __syncthreads();
    int ks = t >> 6, dout = t & 63;
    float ap[8] = {0.f, 0.f, 0.f, 0.f, 0.f, 0.f, 0.f, 0.f};
    float an[8] = {0.f, 0.f, 0.f, 0.f, 0.f, 0.f, 0.f, 0.f};
    for (int k = 0; k < 64; ++k) {
        float w0 = svb[0][k][dout], w1 = svb[1][k][dout];
        #pragma unroll
        for (int c8 = 0; c8 < 8; ++c8) {
            float rc = src[ks * 8 + c8][k];
            ap[c8] += rc * w0;
            an[c8] += rc * w1;
        }
    }
    unsigned int wsh[2] = {0, 0}, wsl[2] = {0, 0}, wdh[2] = {0, 0}, wdl[2] = {0, 0};
    #pragma unroll
    for (int c8 = 0; c8 < 8; ++c8) {
        float s = (ap[c8] + an[c8]) * 0.5f, dv = (ap[c8] - an[c8]) * 0.5f;
        int q_s = (int)rintf(s * 512.f);
        int q_d = (int)rintf(dv * 512.f);
        q_s = min(max(q_s, -32511), 32511);
        q_d = min(max(q_d, -32511), 32511);
        int sh = (q_s + 128) >> 8, sl = q_s - (sh << 8);
        int dh = (q_d + 128) >> 8, dl = q_d - (dh << 8);
        int w = c8 >> 2, sft = (c8 & 3) * 8;
        wsh[w] |= (unsigned int)(sh & 0xFF) << sft;
        wsl[w] |= (unsigned int)(sl & 0xFF) << sft;
        wdh[w] |= (unsigned int)(dh & 0xFF) << sft;
        wdl[w] |= (unsigned int)(dl & 0xFF) << sft;
    }
    int kc = kc32 >> 1;
    int lgw = ((kc32 & 1) << 1) | (ks >> 1);
    size_t off = (((size_t)(b * 128 + kc) * 64 + dout) * 4 + lgw) * 16 + (ks & 1) * 8;
    *(u32x2*)(csh + off) = (u32x2){wsh[0], wsh[1]};
    *(u32x2*)(csl + off) = (u32x2){wsl[0], wsl[1]};
    *(u32x2*)(cdh + off) = (u32x2){wdh[0], wdh[1]};
    *(u32x2*)(cdl + off) = (u32x2){wdl[0], wdl[1]};
}

// ---------------------------------------------------------------------------
// K3: i8 phase B. npart[q][b][v][d] = (|A|@s + A@d)/512 over K-16th q,
// A decoded from comp codes. 128-row 4-wave blocks, 8 K64-chunks,
// gload_lds double-buffer (16 KB dbuf -> 4 blocks/CU). grid 1024 x 256.
// ---------------------------------------------------------------------------
__global__ __launch_bounds__(256, 4) void k_phaseB(
    const unsigned short* __restrict__ comp,
    const char* __restrict__ csh, const char* __restrict__ csl,
    const char* __restrict__ cdh, const char* __restrict__ cdl,
    float* __restrict__ npart)
{
    __shared__ char lds[2][16384];
    int blk = blockIdx.x;
    int combo = blk & 63;
    int rg = blk >> 6;
    int b = combo >> 4;
    int q = combo & 15;
    int t = threadIdx.x;
    int wv = t >> 6, l = t & 63, lr = l & 15, lg = l >> 4;
    int v0 = rg * 128 + wv * 32;
    const unsigned short* compb = comp + (size_t)b * 256 * NC;
    int sh_ = 2 * (lr & 7);
    const unsigned short* cp0 = compb + (size_t)((v0 + lr) >> 3) * NC + q * 512 + lg * 16;
    const unsigned short* cp1 = compb + (size_t)((v0 + 16 + lr) >> 3) * NC + q * 512 + lg * 16;
    const size_t cbase = ((size_t)(b * 128 + q * 8)) * 4096;

    i32x4 ahi[2][4], alo[2][4];
    #pragma unroll
    for (int i = 0; i < 2; ++i)
        #pragma unroll
        for (int j = 0; j < 4; ++j) { ahi[i][j] = (i32x4){0,0,0,0}; alo[i][j] = (i32x4){0,0,0,0}; }

    {
        size_t gb = cbase + (size_t)t * 16;
        char* lp = &lds[0][t * 16];
        gload_lds16(csh + gb, lp);
        gload_lds16(csl + gb, lp + 4096);
        gload_lds16(cdh + gb, lp + 8192);
        gload_lds16(cdl + gb, lp + 12288);
    }
    __syncthreads();

    int cur = 0;
    #pragma unroll 1
    for (int cc = 0; cc < 8; ++cc) {
        // comp codes for this chunk (L2-resident)
        u16x8 u00 = *(const u16x8*)(cp0 + cc * 64);
        u16x8 u01 = *(const u16x8*)(cp0 + cc * 64 + 8);
        u16x8 u10 = *(const u16x8*)(cp1 + cc * 64);
        u16x8 u11 = *(const u16x8*)(cp1 + cc * 64 + 8);
        // stage next chunk into other buffer
        if (cc < 7) {
            size_t gb = cbase + (size_t)(cc + 1) * 4096 + (size_t)t * 16;
            char* lp = &lds[cur ^ 1][t * 16];
            gload_lds16(csh + gb, lp);
            gload_lds16(csl + gb, lp + 4096);
            gload_lds16(cdh + gb, lp + 8192);
            gload_lds16(cdl + gb, lp + 12288);
        }
        // decode A fragments (16 i8 per lane per rt)
        i32x4 Asgn[2], Aabs[2];
        #pragma unroll
        for (int rt = 0; rt < 2; ++rt) {
            u16x8 ua = rt ? u10 : u00;
            u16x8 ub = rt ? u11 : u01;
            i32x4 sg;
            #pragma unroll
            for (int g = 0; g < 4; ++g) {
                unsigned int wg = 0;
                #pragma unroll
                for (int jj = 0; jj < 4; ++jj) {
                    int j = g * 4 + jj;
                    unsigned int code = ((unsigned int)(j < 8 ? ua[j & 7] : ub[j & 7]) >> sh_) & 3u;
                    unsigned int byt = (code == 3u) ? 0xFFu : code;
                    wg |= byt << (jj * 8);
                }
                sg[g] = (int)wg;
            }
            Asgn[rt] = sg;
            i32x4 ab;
            #pragma unroll
            for (int g = 0; g < 4; ++g) ab[g] = sg[g] & 0x01010101;
            Aabs[rt] = ab;
        }
        const char* bufp = lds[cur];
        #pragma unroll
        for (int n = 0; n < 4; ++n) {
            int boff = ((n * 16 + lr) * 4 + lg) * 16;
            i32x4 Bsh = *(const i32x4*)(bufp + boff);
            i32x4 Bsl = *(const i32x4*)(bufp + 4096 + boff);
            i32x4 Bdh = *(const i32x4*)(bufp + 8192 + boff);
            i32x4 Bdl = *(const i32x4*)(bufp + 12288 + boff);
            #pragma unroll
            for (int rt = 0; rt < 2; ++rt) {
                ahi[rt][n] = __builtin_amdgcn_mfma_i32_16x16x64_i8(Aabs[rt], Bsh, ahi[rt][n], 0, 0, 0);
                ahi[rt][n] = __builtin_amdgcn_mfma_i32_16x16x64_i8(Asgn[rt], Bdh, ahi[rt][n], 0, 0, 0);
                alo[rt][n] = __builtin_amdgcn_mfma_i32_16x16x64_i8(Aabs[rt], Bsl, alo[rt][n], 0, 0, 0);
                alo[rt][n] = __builtin_amdgcn_mfma_i32_16x16x64_i8(Asgn[rt], Bdl, alo[rt][n], 0, 0, 0);
            }
        }
        __syncthreads();
        cur ^= 1;
    }
    float* dst = npart + (((size_t)q * NBATCH + b) * NV + v0) * DD;
    #pragma unroll
    for (int rt = 0; rt < 2; ++rt)
        #pragma unroll
        for (int n = 0; n < 4; ++n)
            #pragma unroll
            for (int r = 0; r < 4; ++r) {
                float v = (float)(ahi[rt][n][r] * 256 + alo[rt][n][r]) * (1.0f / 512.0f);
                dst[(size_t)(rt * 16 + lg * 4 + r) * DD + n * 16 + lr] = v;
            }
}

// ---------------------------------------------------------------------------
// K4: v_emb=relu(sum_{q<16} npart+vb); av=tanh([g|v_emb]@Wg^T+bg); GRU -> out
// grid 256 x 512, 4 row-iterations per block (weights staged once).
// ---------------------------------------------------------------------------
__global__ __launch_bounds__(512) void k_gru(
    const float* __restrict__ npart, const float* __restrict__ vars,
    const float* __restrict__ gv, const float* __restrict__ vb,
    const float* __restrict__ Wg, const float* __restrict__ bg,
    const float* __restrict__ Wz, const float* __restrict__ Uz, const float* __restrict__ bz,
    const float* __restrict__ Wr, const float* __restrict__ Ur, const float* __restrict__ brr,
    const float* __restrict__ Wh, const float* __restrict__ Uh, const float* __restrict__ bh,
    float* __restrict__ out)
{
    __shared__ float sWg[72][65];
    __shared__ float sWz[64][65], sUz[64][65];
    __shared__ float sWr[64][65], sUr[64][65];
    __shared__ float sWh[64][65], sUh[64][65];
    __shared__ float scat[8][72];
    __shared__ float sprev[8][64];
    __shared__ float sav[8][64];
    __shared__ float srp[8][64];
    int t = threadIdx.x;
    for (int i = t * 4; i < 4608; i += 2048) {
        fx4 g4 = *(const fx4*)(Wg + i);
        int dout = i / 72, j = i - dout * 72;
        #pragma unroll
        for (int jj = 0; jj < 4; ++jj) sWg[j + jj][dout] = g4[jj];
    }
    for (int i = t * 4; i < 4096; i += 2048) {
        int dout = i >> 6, k = i & 63;
        fx4 a;
        a = *(const fx4*)(Wz + i);
        #pragma unroll
        for (int jj = 0; jj < 4; ++jj) sWz[k + jj][dout] = a[jj];
        a = *(const fx4*)(Uz + i);
        #pragma unroll
        for (int jj = 0; jj < 4; ++jj) sUz[k + jj][dout] = a[jj];
        a = *(const fx4*)(Wr + i);
        #pragma unroll
        for (int jj = 0; jj < 4; ++jj) sWr[k + jj][dout] = a[jj];
        a = *(const fx4*)(Ur + i);
        #pragma unroll
        for (int jj = 0; jj < 4; ++jj) sUr[k + jj][dout] = a[jj];
        a = *(const fx4*)(Wh + i);
        #pragma unroll
        for (int jj = 0; jj < 4; ++jj) sWh[k + jj][dout] = a[jj];
        a = *(const fx4*)(Uh + i);
        #pragma unroll
        for (int jj = 0; jj < 4; ++jj) sUh[k + jj][dout] = a[jj];
    }
    int rr = t >> 6, dout = t & 63;
    const size_t qs = (size_t)NBATCH * NV * DD;
    #pragma unroll 1
    for (int it = 0; it < 4; ++it) {
        size_t row = (size_t)blockIdx.x * 32 + it * 8 + rr;
        float prev = vars[row * 64 + dout];
        float ve = vb[dout];
        #pragma unroll
        for (int s = 0; s < 16; ++s) ve += npart[(size_t)s * qs + row * 64 + dout];
        ve = fmaxf(ve, 0.f);
        scat[rr][8 + dout] = ve;
        if (dout < 8) scat[rr][dout] = gv[row * 8 + dout];
        sprev[rr][dout] = prev;
        __syncthreads();
        float a = bg[dout];
        for (int j = 0; j < 72; ++j) a += scat[rr][j] * sWg[j][dout];
        float av = 1.f - 2.f / (__expf(2.f * a) + 1.f);
        sav[rr][dout] = av;
        __syncthreads();
        float zi = bz[dout], ri = brr[dout], hwa = 0.f;
        for (int k = 0; k < 64; ++k) {
            float ak = sav[rr][k], pk = sprev[rr][k];
            zi += ak * sWz[k][dout] + pk * sUz[k][dout];
            ri += ak * sWr[k][dout] + pk * sUr[k][dout];
            hwa += ak * sWh[k][dout];
        }
        float z = 1.f / (1.f + __expf(-zi));
        float rgate = 1.f / (1.f + __expf(-ri));
        srp[rr][dout] = rgate * prev;
        __syncthreads();
        float hin = bh[dout] + hwa;
        for (int k = 0; k < 64; ++k) hin += srp[rr][k] * sUh[k][dout];
        float ht = 1.f - 2.f / (__expf(2.f * hin) + 1.f);
        out[row * 64 + dout] = (1.f - z) * prev + z * ht;
        __syncthreads();
    }
}

// ---------------------------------------------------------------------------
extern "C" void kernel_launch(void* const* d_in, const int* in_sizes, int n_in,
                              void* d_out, int out_size, void* d_ws, size_t ws_size,
                              hipStream_t stream) {
    (void)in_sizes; (void)n_in; (void)out_size; (void)ws_size;
    const float* vars = (const float*)d_in[0];
    const float* gv   = (const float*)d_in[1];
    const float* cmat = (const float*)d_in[2];
    const float* cblk = (const float*)d_in[4];
    const float* vblk = (const float*)d_in[5];
    const float* vb   = (const float*)d_in[6];
    const float* cb   = (const float*)d_in[7];
    const float* Wg   = (const float*)d_in[8];
    const float* bg   = (const float*)d_in[9];
    const float* Wz   = (const float*)d_in[10];
    const float* Uz   = (const float*)d_in[11];
    const float* bz   = (const float*)d_in[12];
    const float* Wr   = (const float*)d_in[13];
    const float* Ur   = (const float*)d_in[14];
    const float* br_  = (const float*)d_in[15];
    const float* Wh   = (const float*)d_in[16];
    const float* Uh   = (const float*)d_in[17];
    const float* bh   = (const float*)d_in[18];
    float* out = (float*)d_out;

    char* w = (char*)d_ws;
    const size_t MB = 1024 * 1024;
    char* qsh = w + 0 * MB;
    char* qsl = w + 1 * MB;
    char* qdh = w + 2 * MB;
    char* qdl = w + 3 * MB;
    char* csh = w + 4 * MB;      // 2 MB each, i8 planes of cvars
    char* csl = w + 6 * MB;
    char* cdh = w + 8 * MB;
    char* cdl = w + 10 * MB;
    float* cpart         = (float*)(w + 12 * MB);           // 32 MB [4][B][NC][DD]
    float* npart         = (float*)(w + 44 * MB);           // 32 MB [16][B][NV][DD]
    unsigned short* comp = (unsigned short*)(w + 76 * MB);  // 16 MB [B][256][NC]

    k_prep_pv<<<256, 256, 0, stream>>>(vars, cblk, qsh, qsl, qdh, qdl);
    k_phaseA<<<1024, 256, 0, stream>>>(cmat, qsh, qsl, qdh, qdl, cpart, comp);
    k_projC<<<1024, 256, 0, stream>>>(cpart, cb, vblk, csh, csl, cdh, cdl);
    k_phaseB<<<1024, 256, 0, stream>>>(comp, csh, csl, cdh, cdl, npart);
    k_gru<<<256, 512, 0, stream>>>(npart, vars, gv, vb, Wg, bg,
                                   Wz, Uz, bz, Wr, Ur, br_, Wh, Uh, bh, out);
}